// Round 1
// 1025.746 us; speedup vs baseline: 1.2032x; 1.2032x over previous
//
#include <hip/hip_runtime.h>
#include <stdint.h>

#define N_PTS 8192
#define B_SZ 8
#define NPOINT_ 1024
#define NSAMPLE_ 32
#define NPROD 8            // producer blocks (one per batch) — bit-exact R9 FPS
#define NCONS 240          // consumer blocks (ballquery + MLP), 1 block/CU by LDS
#define CWAVES (NCONS * 8) // 1920 consumer waves
#define PUBK 64            // publish progress every 64 FPS iterations

typedef float __attribute__((ext_vector_type(2))) f32x2;

// DPP helpers: combine with self via update_dpp (invalid lanes keep self -> no-op).
template <int CTRL>
__device__ __forceinline__ float dpp_maxf(float v) {
    int o = __builtin_amdgcn_update_dpp(__float_as_int(v), __float_as_int(v),
                                        CTRL, 0xf, 0xf, false);
    return fmaxf(v, __int_as_float(o));
}
template <int CTRL>
__device__ __forceinline__ int dpp_mini(int v) {
    int o = __builtin_amdgcn_update_dpp(v, v, CTRL, 0xf, 0xf, false);
    return (o < v) ? o : v;
}

// Agent-scope (device-coherent, sc1) float load/store — cross-XCD visible.
__device__ __forceinline__ float ld_coh(const float* p) {
    return __int_as_float(__hip_atomic_load((int*)p, __ATOMIC_RELAXED,
                                            __HIP_MEMORY_SCOPE_AGENT));
}
__device__ __forceinline__ void st_coh(float* p, float v) {
    __hip_atomic_store((int*)p, __float_as_int(v), __ATOMIC_RELAXED,
                       __HIP_MEMORY_SCOPE_AGENT);
}

// ---- shared-memory union layout (bytes). Producer and consumer roles overlap.
#define SM_SPTS 0        // float4[8192]            = 131072   (producer)
#define SM_CVAL 131072   // float[2][8]             = 64       (producer)
#define SM_CIDX 131136   // int[2][8]               = 64       (producer)
#define SM_W1 0          // float[64*68]            = 17408    (consumer)
#define SM_W2 17408      // float[64*64]            = 16384
#define SM_W3 33792      // float[128*64]           = 32768
#define SM_B1 66560      // float[64]
#define SM_B2 66816      // float[64]
#define SM_B3 67072      // float[128]
#define SM_XB 67584      // float[8][16*68]         = 34816
#define SM_HB 102400     // float[8][16*68]         = 34816
#define SM_NIDX 137216   // int[8][32]              = 1024
#define SM_TOTAL 138240  // < 160 KiB -> exactly 1 block/CU

__global__ __launch_bounds__(512, 2) void fused_kernel(
    const float* __restrict__ xyz, const float* __restrict__ feat,
    const float* __restrict__ w1, const float* __restrict__ b1,
    const float* __restrict__ w2, const float* __restrict__ b2,
    const float* __restrict__ w3, const float* __restrict__ b3,
    float* __restrict__ new_xyz, float* __restrict__ out,
    int* __restrict__ prog) {
    __shared__ __align__(16) char smem[SM_TOTAL];
    const int t = threadIdx.x;
    const int wave = t >> 6, lane = t & 63;

    if (blockIdx.x < NPROD) {
        // ===================== FPS producer (bit-exact R9 path) ==============
        float4* spts = (float4*)smem;
        float* cval = (float*)(smem + SM_CVAL);  // [2][8] -> buf*8+w
        int* cidx = (int*)(smem + SM_CIDX);
        const int b = blockIdx.x;
        const float* bx = xyz + (size_t)b * N_PTS * 3;
        int* pp = prog + b * 64;  // padded: one cache line per batch

        f32x2 px[8], py[8], pz[8], dst[8];
#pragma unroll
        for (int jj = 0; jj < 8; ++jj) {
            int p0 = t + 512 * (2 * jj);
            int p1 = t + 512 * (2 * jj + 1);
            float x0 = bx[3 * p0 + 0], y0 = bx[3 * p0 + 1], z0 = bx[3 * p0 + 2];
            float x1 = bx[3 * p1 + 0], y1 = bx[3 * p1 + 1], z1 = bx[3 * p1 + 2];
            spts[p0] = make_float4(x0, y0, z0, 0.0f);
            spts[p1] = make_float4(x1, y1, z1, 0.0f);
            px[jj] = f32x2{x0, x1};
            py[jj] = f32x2{y0, y1};
            pz[jj] = f32x2{z0, z1};
            dst[jj] = f32x2{1e10f, 1e10f};
        }
        __syncthreads();

        float cx = bx[0], cy = bx[1], cz = bx[2];
        if (t == 0) {
            st_coh(&new_xyz[(b * NPOINT_) * 3 + 0], cx);
            st_coh(&new_xyz[(b * NPOINT_) * 3 + 1], cy);
            st_coh(&new_xyz[(b * NPOINT_) * 3 + 2], cz);
        }

        for (int it = 1; it < NPOINT_; ++it) {
            // ---- packed distance update (bit-exact vs scalar rn ops)
            f32x2 cx2 = f32x2{cx, cx}, cy2 = f32x2{cy, cy}, cz2 = f32x2{cz, cz};
            {
#pragma clang fp contract(off)
#pragma unroll
                for (int jj = 0; jj < 8; ++jj) {
                    f32x2 dx = px[jj] - cx2;
                    f32x2 dy = py[jj] - cy2;
                    f32x2 dz = pz[jj] - cz2;
                    f32x2 d = (dx * dx + dy * dy) + dz * dz;
                    dst[jj] = __builtin_elementwise_min(dst[jj], d);
                }
            }
            // ---- in-thread max value
            f32x2 m01 = __builtin_elementwise_max(dst[0], dst[1]);
            f32x2 m23 = __builtin_elementwise_max(dst[2], dst[3]);
            f32x2 m45 = __builtin_elementwise_max(dst[4], dst[5]);
            f32x2 m67 = __builtin_elementwise_max(dst[6], dst[7]);
            f32x2 m03 = __builtin_elementwise_max(m01, m23);
            f32x2 m47 = __builtin_elementwise_max(m45, m67);
            f32x2 mm = __builtin_elementwise_max(m03, m47);
            float bv = fmaxf(mm.x, mm.y);
            // ---- smallest local index attaining bv
            int lj = 0;
#pragma unroll
            for (int jj = 7; jj >= 0; --jj) {
                lj = (dst[jj].y == bv) ? 2 * jj + 1 : lj;
                lj = (dst[jj].x == bv) ? 2 * jj : lj;
            }
            int idx = (lj << 9) + t;

            // ---- wave reduce: max value -> lane 63
            float mv = bv;
            mv = dpp_maxf<0x111>(mv);
            mv = dpp_maxf<0x112>(mv);
            mv = dpp_maxf<0x114>(mv);
            mv = dpp_maxf<0x118>(mv);
            mv = dpp_maxf<0x142>(mv);
            mv = dpp_maxf<0x143>(mv);
            float wmax = __int_as_float(
                __builtin_amdgcn_readlane(__float_as_int(mv), 63));
            int ic = (bv == wmax) ? idx : 0x7FFFFFFF;
            ic = dpp_mini<0x111>(ic);
            ic = dpp_mini<0x112>(ic);
            ic = dpp_mini<0x114>(ic);
            ic = dpp_mini<0x118>(ic);
            ic = dpp_mini<0x142>(ic);
            ic = dpp_mini<0x143>(ic);

            const int buf = it & 1;
            if (lane == 63) {
                cval[buf * 8 + wave] = wmax;
                cidx[buf * 8 + wave] = ic;
            }
            __syncthreads();

            // ---- cross-wave reduce over 8 candidates
            float cv = cval[buf * 8 + (lane & 7)];
            int ci = cidx[buf * 8 + (lane & 7)];
            float gm = cv;
            gm = dpp_maxf<0x111>(gm);
            gm = dpp_maxf<0x112>(gm);
            gm = dpp_maxf<0x114>(gm);
            float gmax =
                __int_as_float(__builtin_amdgcn_readlane(__float_as_int(gm), 7));
            int ic2 = (cv == gmax) ? ci : 0x7FFFFFFF;
            ic2 = dpp_mini<0x111>(ic2);
            ic2 = dpp_mini<0x112>(ic2);
            ic2 = dpp_mini<0x114>(ic2);
            int wi = __builtin_amdgcn_readlane(ic2, 7);

            float4 sp = spts[wi];  // uniform broadcast, conflict-free
            cx = sp.x;
            cy = sp.y;
            cz = sp.z;
            if (t == 0) {
                st_coh(&new_xyz[(b * NPOINT_ + it) * 3 + 0], cx);
                st_coh(&new_xyz[(b * NPOINT_ + it) * 3 + 1], cy);
                st_coh(&new_xyz[(b * NPOINT_ + it) * 3 + 2], cz);
                if ((it & (PUBK - 1)) == (PUBK - 1)) {
                    // release: prior sc1 centroid stores visible before flag
                    __hip_atomic_store(pp, it + 1, __ATOMIC_RELEASE,
                                       __HIP_MEMORY_SCOPE_AGENT);
                }
            }
        }
    } else {
        // ===================== consumer: ballquery + gather + MLP ============
        float* lw1T = (float*)(smem + SM_W1);
        float* lw2T = (float*)(smem + SM_W2);
        float* lw3T = (float*)(smem + SM_W3);
        float* lb1 = (float*)(smem + SM_B1);
        float* lb2 = (float*)(smem + SM_B2);
        float* lb3 = (float*)(smem + SM_B3);

        for (int i = t; i < 67 * 64; i += 512) {
            int k = i >> 6, c = i & 63;
            lw1T[c * 68 + k] = w1[i];
        }
        if (t < 64) lw1T[t * 68 + 67] = 0.0f;
        for (int i = t; i < 64 * 64; i += 512) {
            int k = i >> 6, c = i & 63;
            lw2T[c * 64 + k] = w2[i];
        }
        for (int i = t; i < 64 * 128; i += 512) {
            int k = i >> 7, c = i & 127;
            lw3T[c * 64 + k] = w3[i];
        }
        if (t < 64) {
            lb1[t] = b1[t];
            lb2[t] = b2[t];
        }
        if (t < 128) lb3[t] = b3[t];
        __syncthreads();

        float* xw = (float*)(smem + SM_XB) + wave * (16 * 68);
        float* hw = (float*)(smem + SM_HB) + wave * (16 * 68);
        int* nw = (int*)(smem + SM_NIDX) + wave * 32;
        const float* wc1 = lw1T + lane * 68;
        const float* wc2 = lw2T + lane * 64;
        const float* wca = lw3T + lane * 64;
        const float* wcb = lw3T + (lane + 64) * 64;

        const int widx = (blockIdx.x - NPROD) * 8 + wave;
        for (int cc = widx; cc < B_SZ * NPOINT_; cc += CWAVES) {
            const int s = cc >> 3, b = cc & 7;  // s monotone per wave
            const int g = (b << 10) + s;
            int* pp = prog + b * 64;

            // ---- wait for centroid s of batch b (throttled sc1 polling)
            int pv = __hip_atomic_load(pp, __ATOMIC_RELAXED,
                                       __HIP_MEMORY_SCOPE_AGENT);
            while (pv <= s) {
                if (s - pv >= 64)
                    __builtin_amdgcn_s_sleep(64);
                else
                    __builtin_amdgcn_s_sleep(16);
                pv = __hip_atomic_load(pp, __ATOMIC_RELAXED,
                                       __HIP_MEMORY_SCOPE_AGENT);
            }
            __builtin_amdgcn_fence(__ATOMIC_ACQUIRE, "agent");
            const float cx = ld_coh(&new_xyz[g * 3 + 0]);
            const float cy = ld_coh(&new_xyz[g * 3 + 1]);
            const float cz = ld_coh(&new_xyz[g * 3 + 2]);

            // ---- ball query (exact arithmetic of the standalone kernel;
            //      xyz read from global — L2/L3-resident, no LDS staging)
            const float* bx = xyz + (size_t)b * N_PTS * 3;
            const float r2 = 0.04f;
            int taken = 0, firstIdx = -1;
            for (int ch = 0; ch < N_PTS / 64 && taken < NSAMPLE_; ++ch) {
                int p = ch * 64 + lane;
                float dxq = __fsub_rn(bx[3 * p + 0], cx);
                float dyq = __fsub_rn(bx[3 * p + 1], cy);
                float dzq = __fsub_rn(bx[3 * p + 2], cz);
                float sq = __fadd_rn(
                    __fadd_rn(__fmul_rn(dxq, dxq), __fmul_rn(dyq, dyq)),
                    __fmul_rn(dzq, dzq));
                bool pred = !(sq > r2);
                unsigned long long mask = __ballot(pred);
                if (mask) {
                    int cnt = __popcll(mask);
                    if (firstIdx < 0) firstIdx = ch * 64 + (__ffsll(mask) - 1);
                    if (pred) {
                        int pos =
                            taken + __popcll(mask & ((1ull << lane) - 1ull));
                        if (pos < NSAMPLE_) nw[pos] = p;
                    }
                    taken += cnt;
                }
            }
            if (lane >= taken && lane < NSAMPLE_) nw[lane] = firstIdx;
            asm volatile("s_waitcnt lgkmcnt(0)" ::: "memory");

            // ---- gather + MLP(67->64->64->128, relu) + max over 32 samples
            float mo0 = 0.0f, mo1 = 0.0f;
            for (int half = 0; half < 2; ++half) {
                int iis[16];
#pragma unroll
                for (int r = 0; r < 16; ++r) iis[r] = nw[half * 16 + r];
#pragma unroll
                for (int r = 0; r < 16; ++r) {
                    xw[r * 68 + 3 + lane] =
                        feat[((size_t)b * N_PTS + iis[r]) * 64 + lane];
                    if (lane < 3) {
                        float pv2 = xyz[((size_t)b * N_PTS + iis[r]) * 3 + lane];
                        float cv = (lane == 0) ? cx : ((lane == 1) ? cy : cz);
                        xw[r * 68 + lane] = pv2 - cv;
                    }
                    if (lane == 0) xw[r * 68 + 67] = 0.0f;
                }
                f32x2 acc2[16];
                // ---- L1: 68(padded)->64
                {
                    float bias = lb1[lane];
#pragma unroll
                    for (int r = 0; r < 16; ++r) acc2[r] = f32x2{bias, 0.0f};
                    for (int kk = 0; kk < 68; kk += 4) {
                        f32x2 wA = *(const f32x2*)(wc1 + kk);
                        f32x2 wB = *(const f32x2*)(wc1 + kk + 2);
#pragma unroll
                        for (int r = 0; r < 16; ++r) {
                            float4 xv = *(const float4*)&xw[r * 68 + kk];
                            f32x2 xa = f32x2{xv.x, xv.y};
                            f32x2 xc = f32x2{xv.z, xv.w};
                            acc2[r] = xa * wA + acc2[r];
                            acc2[r] = xc * wB + acc2[r];
                        }
                    }
#pragma unroll
                    for (int r = 0; r < 16; ++r)
                        hw[r * 68 + lane] = fmaxf(acc2[r].x + acc2[r].y, 0.0f);
                }
                // ---- L2: 64->64
                {
                    float bias = lb2[lane];
#pragma unroll
                    for (int r = 0; r < 16; ++r) acc2[r] = f32x2{bias, 0.0f};
                    for (int kk = 0; kk < 64; kk += 4) {
                        f32x2 wA = *(const f32x2*)(wc2 + kk);
                        f32x2 wB = *(const f32x2*)(wc2 + kk + 2);
#pragma unroll
                        for (int r = 0; r < 16; ++r) {
                            float4 hv = *(const float4*)&hw[r * 68 + kk];
                            f32x2 xa = f32x2{hv.x, hv.y};
                            f32x2 xc = f32x2{hv.z, hv.w};
                            acc2[r] = xa * wA + acc2[r];
                            acc2[r] = xc * wB + acc2[r];
                        }
                    }
#pragma unroll
                    for (int r = 0; r < 16; ++r)
                        xw[r * 68 + lane] = fmaxf(acc2[r].x + acc2[r].y, 0.0f);
                }
                // ---- L3: 64->128, lane owns cols lane and lane+64
                {
                    f32x2 a2[16], c2[16];
                    float bb0 = lb3[lane], bb1 = lb3[lane + 64];
#pragma unroll
                    for (int r = 0; r < 16; ++r) {
                        a2[r] = f32x2{bb0, 0.0f};
                        c2[r] = f32x2{bb1, 0.0f};
                    }
                    for (int kk = 0; kk < 64; kk += 4) {
                        f32x2 wA0 = *(const f32x2*)(wca + kk);
                        f32x2 wB0 = *(const f32x2*)(wca + kk + 2);
                        f32x2 wA1 = *(const f32x2*)(wcb + kk);
                        f32x2 wB1 = *(const f32x2*)(wcb + kk + 2);
#pragma unroll
                        for (int r = 0; r < 16; ++r) {
                            float4 hv = *(const float4*)&xw[r * 68 + kk];
                            f32x2 xa = f32x2{hv.x, hv.y};
                            f32x2 xc = f32x2{hv.z, hv.w};
                            a2[r] = xa * wA0 + a2[r];
                            a2[r] = xc * wB0 + a2[r];
                            c2[r] = xa * wA1 + c2[r];
                            c2[r] = xc * wB1 + c2[r];
                        }
                    }
#pragma unroll
                    for (int r = 0; r < 16; ++r) {
                        mo0 = fmaxf(mo0, fmaxf(a2[r].x + a2[r].y, 0.0f));
                        mo1 = fmaxf(mo1, fmaxf(c2[r].x + c2[r].y, 0.0f));
                    }
                }
            }
            out[((size_t)b * 128 + lane) * 1024 + s] = mo0;
            out[((size_t)b * 128 + lane + 64) * 1024 + s] = mo1;
        }
    }
}

extern "C" void kernel_launch(void* const* d_in, const int* in_sizes, int n_in,
                              void* d_out, int out_size, void* d_ws,
                              size_t ws_size, hipStream_t stream) {
    const float* xyz = (const float*)d_in[0];
    const float* feat = (const float*)d_in[1];
    const float* w1 = (const float*)d_in[2];
    const float* b1 = (const float*)d_in[3];
    const float* w2 = (const float*)d_in[4];
    const float* b2 = (const float*)d_in[5];
    const float* w3 = (const float*)d_in[6];
    const float* b3 = (const float*)d_in[7];

    float* out_xyz = (float*)d_out;                       // (8,1024,3)
    float* out_feat = (float*)d_out + B_SZ * NPOINT_ * 3; // (8,128,1024)
    int* prog = (int*)d_ws;  // 8 progress counters, 256B apart

    hipMemsetAsync(d_ws, 0, NPROD * 64 * sizeof(int), stream);
    fused_kernel<<<NPROD + NCONS, 512, 0, stream>>>(
        xyz, feat, w1, b1, w2, b2, w3, b3, out_xyz, out_feat, prog);
}

// Round 2
// 1023.026 us; speedup vs baseline: 1.2064x; 1.0027x over previous
//
#include <hip/hip_runtime.h>
#include <stdint.h>

#define N_PTS 8192
#define B_SZ 8
#define NPOINT_ 1024
#define NSAMPLE_ 32
#define NPROD 8            // producer blocks (one per batch) — bit-exact R9 FPS
#define NCONS 240          // consumer blocks (ballquery + MLP), 1 block/CU by LDS
#define CWAVES (NCONS * 8) // 1920 consumer waves

typedef float __attribute__((ext_vector_type(2))) f32x2;

// DPP helpers: combine with self via update_dpp (invalid lanes keep self -> no-op).
template <int CTRL>
__device__ __forceinline__ float dpp_maxf(float v) {
    int o = __builtin_amdgcn_update_dpp(__float_as_int(v), __float_as_int(v),
                                        CTRL, 0xf, 0xf, false);
    return fmaxf(v, __int_as_float(o));
}
template <int CTRL>
__device__ __forceinline__ int dpp_mini(int v) {
    int o = __builtin_amdgcn_update_dpp(v, v, CTRL, 0xf, 0xf, false);
    return (o < v) ? o : v;
}

// Agent-scope (device-coherent, sc1) float load/store — cross-XCD visible.
__device__ __forceinline__ float ld_coh(const float* p) {
    return __int_as_float(__hip_atomic_load((int*)p, __ATOMIC_RELAXED,
                                            __HIP_MEMORY_SCOPE_AGENT));
}
__device__ __forceinline__ void st_coh(float* p, float v) {
    __hip_atomic_store((int*)p, __float_as_int(v), __ATOMIC_RELAXED,
                       __HIP_MEMORY_SCOPE_AGENT);
}

// ---- shared-memory union layout (bytes). Producer and consumer roles overlap.
// Producer: spts float4[8192]=131072, cval/cidx 128 -> 131200 B
// Consumer (padded weight strides: w1 70, w2/w3 66 floats -> 4-way conflicts max)
#define SM_SPTS 0
#define SM_CVAL 131072
#define SM_CIDX 131136
#define SM_W1 0          // float[64*70]  = 17920
#define SM_W2 17920      // float[64*66]  = 16896
#define SM_W3 34816      // float[128*66] = 33792
#define SM_B1 68608      // float[64]
#define SM_B2 68864      // float[64]
#define SM_B3 69120      // float[128]
#define SM_XB 69632      // float[8][16*68] = 34816
#define SM_HB 104448     // float[8][16*68] = 34816
#define SM_NIDX 139264   // int[8][32]      = 1024
#define SM_TOTAL 140288  // < 160 KiB -> exactly 1 block/CU

#define W1S 70
#define W2S 66
#define W3S 66

__global__ __launch_bounds__(512, 2) void fused_kernel(
    const float* __restrict__ xyz, const float* __restrict__ feat,
    const float* __restrict__ w1, const float* __restrict__ b1,
    const float* __restrict__ w2, const float* __restrict__ b2,
    const float* __restrict__ w3, const float* __restrict__ b3,
    float* __restrict__ new_xyz, float* __restrict__ out,
    int* __restrict__ prog) {
    __shared__ __align__(16) char smem[SM_TOTAL];
    const int t = threadIdx.x;
    const int wave = t >> 6, lane = t & 63;

    if (blockIdx.x < NPROD) {
        // ===================== FPS producer (bit-exact R9 path) ==============
        float4* spts = (float4*)smem;
        float* cval = (float*)(smem + SM_CVAL);  // [2][8] -> buf*8+w
        int* cidx = (int*)(smem + SM_CIDX);
        const int b = blockIdx.x;
        const float* bx = xyz + (size_t)b * N_PTS * 3;
        int* pp = prog + b * 64;  // padded: one cache line per batch

        f32x2 px[8], py[8], pz[8], dst[8];
#pragma unroll
        for (int jj = 0; jj < 8; ++jj) {
            int p0 = t + 512 * (2 * jj);
            int p1 = t + 512 * (2 * jj + 1);
            float x0 = bx[3 * p0 + 0], y0 = bx[3 * p0 + 1], z0 = bx[3 * p0 + 2];
            float x1 = bx[3 * p1 + 0], y1 = bx[3 * p1 + 1], z1 = bx[3 * p1 + 2];
            spts[p0] = make_float4(x0, y0, z0, 0.0f);
            spts[p1] = make_float4(x1, y1, z1, 0.0f);
            px[jj] = f32x2{x0, x1};
            py[jj] = f32x2{y0, y1};
            pz[jj] = f32x2{z0, z1};
            dst[jj] = f32x2{1e10f, 1e10f};
        }
        __syncthreads();

        float cx = bx[0], cy = bx[1], cz = bx[2];
        // centroid 0 (point index 0) is written by the first group flush.
        int hold = 0;  // wave0: per-lane captured centroid index for this group

        for (int it = 1; it < NPOINT_; ++it) {
            // ---- packed distance update (bit-exact vs scalar rn ops)
            f32x2 cx2 = f32x2{cx, cx}, cy2 = f32x2{cy, cy}, cz2 = f32x2{cz, cz};
            {
#pragma clang fp contract(off)
#pragma unroll
                for (int jj = 0; jj < 8; ++jj) {
                    f32x2 dx = px[jj] - cx2;
                    f32x2 dy = py[jj] - cy2;
                    f32x2 dz = pz[jj] - cz2;
                    f32x2 d = (dx * dx + dy * dy) + dz * dz;
                    dst[jj] = __builtin_elementwise_min(dst[jj], d);
                }
            }
            // ---- in-thread max value
            f32x2 m01 = __builtin_elementwise_max(dst[0], dst[1]);
            f32x2 m23 = __builtin_elementwise_max(dst[2], dst[3]);
            f32x2 m45 = __builtin_elementwise_max(dst[4], dst[5]);
            f32x2 m67 = __builtin_elementwise_max(dst[6], dst[7]);
            f32x2 m03 = __builtin_elementwise_max(m01, m23);
            f32x2 m47 = __builtin_elementwise_max(m45, m67);
            f32x2 mm = __builtin_elementwise_max(m03, m47);
            float bv = fmaxf(mm.x, mm.y);
            // ---- smallest local index attaining bv
            int lj = 0;
#pragma unroll
            for (int jj = 7; jj >= 0; --jj) {
                lj = (dst[jj].y == bv) ? 2 * jj + 1 : lj;
                lj = (dst[jj].x == bv) ? 2 * jj : lj;
            }
            int idx = (lj << 9) + t;

            // ---- wave reduce: max value -> lane 63
            float mv = bv;
            mv = dpp_maxf<0x111>(mv);
            mv = dpp_maxf<0x112>(mv);
            mv = dpp_maxf<0x114>(mv);
            mv = dpp_maxf<0x118>(mv);
            mv = dpp_maxf<0x142>(mv);
            mv = dpp_maxf<0x143>(mv);
            float wmax = __int_as_float(
                __builtin_amdgcn_readlane(__float_as_int(mv), 63));
            int ic = (bv == wmax) ? idx : 0x7FFFFFFF;
            ic = dpp_mini<0x111>(ic);
            ic = dpp_mini<0x112>(ic);
            ic = dpp_mini<0x114>(ic);
            ic = dpp_mini<0x118>(ic);
            ic = dpp_mini<0x142>(ic);
            ic = dpp_mini<0x143>(ic);

            const int buf = it & 1;
            if (lane == 63) {
                cval[buf * 8 + wave] = wmax;
                cidx[buf * 8 + wave] = ic;
            }
            __syncthreads();

            // ---- publish previous group: wave0's flush stores were drained by
            //      the barrier above (implicit vmcnt(0)) -> plain relaxed store
            //      acts as a release with zero extra waitcnt on the hot path.
            if ((it & 63) == 0 && t == 0) {
                __hip_atomic_store(pp, it, __ATOMIC_RELAXED,
                                   __HIP_MEMORY_SCOPE_AGENT);
            }

            // ---- cross-wave reduce over 8 candidates
            float cv = cval[buf * 8 + (lane & 7)];
            int ci = cidx[buf * 8 + (lane & 7)];
            float gm = cv;
            gm = dpp_maxf<0x111>(gm);
            gm = dpp_maxf<0x112>(gm);
            gm = dpp_maxf<0x114>(gm);
            float gmax =
                __int_as_float(__builtin_amdgcn_readlane(__float_as_int(gm), 7));
            int ic2 = (cv == gmax) ? ci : 0x7FFFFFFF;
            ic2 = dpp_mini<0x111>(ic2);
            ic2 = dpp_mini<0x112>(ic2);
            ic2 = dpp_mini<0x114>(ic2);
            int wi = __builtin_amdgcn_readlane(ic2, 7);

            // capture centroid index `it` in lane (it & 63) of every wave
            hold = (lane == (it & 63)) ? wi : hold;

            float4 sp = spts[wi];  // uniform broadcast, conflict-free
            cx = sp.x;
            cy = sp.y;
            cz = sp.z;

            // ---- group flush: wave0 writes 64 centroids; stores drain at the
            //      NEXT iteration's barrier, publish happens after that barrier.
            if ((it & 63) == 63 && wave == 0) {
                float4 me = spts[hold];
                int s0 = b * NPOINT_ + (it - 63) + lane;
                st_coh(&new_xyz[s0 * 3 + 0], me.x);
                st_coh(&new_xyz[s0 * 3 + 1], me.y);
                st_coh(&new_xyz[s0 * 3 + 2], me.z);
            }
        }
        // final group (it=1023 flush) publish: drain then flag
        __syncthreads();
        if (t == 0) {
            __hip_atomic_store(pp, NPOINT_, __ATOMIC_RELAXED,
                               __HIP_MEMORY_SCOPE_AGENT);
        }
    } else {
        // ===================== consumer: ballquery + gather + MLP ============
        float* lw1T = (float*)(smem + SM_W1);
        float* lw2T = (float*)(smem + SM_W2);
        float* lw3T = (float*)(smem + SM_W3);
        float* lb1 = (float*)(smem + SM_B1);
        float* lb2 = (float*)(smem + SM_B2);
        float* lb3 = (float*)(smem + SM_B3);

        for (int i = t; i < 67 * 64; i += 512) {
            int k = i >> 6, c = i & 63;
            lw1T[c * W1S + k] = w1[i];
        }
        if (t < 64) lw1T[t * W1S + 67] = 0.0f;
        for (int i = t; i < 64 * 64; i += 512) {
            int k = i >> 6, c = i & 63;
            lw2T[c * W2S + k] = w2[i];
        }
        for (int i = t; i < 64 * 128; i += 512) {
            int k = i >> 7, c = i & 127;
            lw3T[c * W3S + k] = w3[i];
        }
        if (t < 64) {
            lb1[t] = b1[t];
            lb2[t] = b2[t];
        }
        if (t < 128) lb3[t] = b3[t];
        __syncthreads();

        float* xw = (float*)(smem + SM_XB) + wave * (16 * 68);
        float* hw = (float*)(smem + SM_HB) + wave * (16 * 68);
        int* nw = (int*)(smem + SM_NIDX) + wave * 32;
        const float* wc1 = lw1T + lane * W1S;
        const float* wc2 = lw2T + lane * W2S;
        const float* wca = lw3T + lane * W3S;
        const float* wcb = lw3T + (lane + 64) * W3S;

        const int widx = (blockIdx.x - NPROD) * 8 + wave;
        for (int cc = widx; cc < B_SZ * NPOINT_; cc += CWAVES) {
            const int s = cc >> 3, b = cc & 7;  // s monotone per wave
            const int g = (b << 10) + s;
            int* pp = prog + b * 64;

            // ---- wait for centroid s of batch b (throttled sc1 polling)
            int pv = __hip_atomic_load(pp, __ATOMIC_RELAXED,
                                       __HIP_MEMORY_SCOPE_AGENT);
            while (pv <= s) {
                if (s - pv >= 64)
                    __builtin_amdgcn_s_sleep(64);
                else
                    __builtin_amdgcn_s_sleep(16);
                pv = __hip_atomic_load(pp, __ATOMIC_RELAXED,
                                       __HIP_MEMORY_SCOPE_AGENT);
            }
            __builtin_amdgcn_fence(__ATOMIC_ACQUIRE, "agent");
            const float cx = ld_coh(&new_xyz[g * 3 + 0]);
            const float cy = ld_coh(&new_xyz[g * 3 + 1]);
            const float cz = ld_coh(&new_xyz[g * 3 + 2]);

            // ---- ball query (exact arithmetic; xyz from global, L2-resident)
            const float* bx = xyz + (size_t)b * N_PTS * 3;
            const float r2 = 0.04f;
            int taken = 0, firstIdx = -1;
            for (int ch = 0; ch < N_PTS / 64 && taken < NSAMPLE_; ++ch) {
                int p = ch * 64 + lane;
                float dxq = __fsub_rn(bx[3 * p + 0], cx);
                float dyq = __fsub_rn(bx[3 * p + 1], cy);
                float dzq = __fsub_rn(bx[3 * p + 2], cz);
                float sq = __fadd_rn(
                    __fadd_rn(__fmul_rn(dxq, dxq), __fmul_rn(dyq, dyq)),
                    __fmul_rn(dzq, dzq));
                bool pred = !(sq > r2);
                unsigned long long mask = __ballot(pred);
                if (mask) {
                    int cnt = __popcll(mask);
                    if (firstIdx < 0) firstIdx = ch * 64 + (__ffsll(mask) - 1);
                    if (pred) {
                        int pos =
                            taken + __popcll(mask & ((1ull << lane) - 1ull));
                        if (pos < NSAMPLE_) nw[pos] = p;
                    }
                    taken += cnt;
                }
            }
            if (lane >= taken && lane < NSAMPLE_) nw[lane] = firstIdx;
            asm volatile("s_waitcnt lgkmcnt(0)" ::: "memory");

            // ---- gather + MLP(67->64->64->128, relu) + max over 32 samples
            float mo0 = 0.0f, mo1 = 0.0f;
            for (int half = 0; half < 2; ++half) {
                int iis[16];
#pragma unroll
                for (int r = 0; r < 16; ++r) iis[r] = nw[half * 16 + r];
#pragma unroll
                for (int r = 0; r < 16; ++r) {
                    xw[r * 68 + 3 + lane] =
                        feat[((size_t)b * N_PTS + iis[r]) * 64 + lane];
                    if (lane < 3) {
                        float pv2 = xyz[((size_t)b * N_PTS + iis[r]) * 3 + lane];
                        float cv = (lane == 0) ? cx : ((lane == 1) ? cy : cz);
                        xw[r * 68 + lane] = pv2 - cv;
                    }
                    if (lane == 0) xw[r * 68 + 67] = 0.0f;
                }
                f32x2 acc2[16];
                // ---- L1: 68(padded)->64
                {
                    float bias = lb1[lane];
#pragma unroll
                    for (int r = 0; r < 16; ++r) acc2[r] = f32x2{bias, 0.0f};
                    for (int kk = 0; kk < 68; kk += 4) {
                        f32x2 wA = *(const f32x2*)(wc1 + kk);
                        f32x2 wB = *(const f32x2*)(wc1 + kk + 2);
#pragma unroll
                        for (int r = 0; r < 16; ++r) {
                            float4 xv = *(const float4*)&xw[r * 68 + kk];
                            f32x2 xa = f32x2{xv.x, xv.y};
                            f32x2 xc = f32x2{xv.z, xv.w};
                            acc2[r] = xa * wA + acc2[r];
                            acc2[r] = xc * wB + acc2[r];
                        }
                    }
#pragma unroll
                    for (int r = 0; r < 16; ++r)
                        hw[r * 68 + lane] = fmaxf(acc2[r].x + acc2[r].y, 0.0f);
                }
                // ---- L2: 64->64
                {
                    float bias = lb2[lane];
#pragma unroll
                    for (int r = 0; r < 16; ++r) acc2[r] = f32x2{bias, 0.0f};
                    for (int kk = 0; kk < 64; kk += 4) {
                        f32x2 wA = *(const f32x2*)(wc2 + kk);
                        f32x2 wB = *(const f32x2*)(wc2 + kk + 2);
#pragma unroll
                        for (int r = 0; r < 16; ++r) {
                            float4 hv = *(const float4*)&hw[r * 68 + kk];
                            f32x2 xa = f32x2{hv.x, hv.y};
                            f32x2 xc = f32x2{hv.z, hv.w};
                            acc2[r] = xa * wA + acc2[r];
                            acc2[r] = xc * wB + acc2[r];
                        }
                    }
#pragma unroll
                    for (int r = 0; r < 16; ++r)
                        xw[r * 68 + lane] = fmaxf(acc2[r].x + acc2[r].y, 0.0f);
                }
                // ---- L3: 64->128, lane owns cols lane and lane+64
                {
                    f32x2 a2[16], c2[16];
                    float bb0 = lb3[lane], bb1 = lb3[lane + 64];
#pragma unroll
                    for (int r = 0; r < 16; ++r) {
                        a2[r] = f32x2{bb0, 0.0f};
                        c2[r] = f32x2{bb1, 0.0f};
                    }
                    for (int kk = 0; kk < 64; kk += 4) {
                        f32x2 wA0 = *(const f32x2*)(wca + kk);
                        f32x2 wB0 = *(const f32x2*)(wca + kk + 2);
                        f32x2 wA1 = *(const f32x2*)(wcb + kk);
                        f32x2 wB1 = *(const f32x2*)(wcb + kk + 2);
#pragma unroll
                        for (int r = 0; r < 16; ++r) {
                            float4 hv = *(const float4*)&xw[r * 68 + kk];
                            f32x2 xa = f32x2{hv.x, hv.y};
                            f32x2 xc = f32x2{hv.z, hv.w};
                            a2[r] = xa * wA0 + a2[r];
                            a2[r] = xc * wB0 + a2[r];
                            c2[r] = xa * wA1 + c2[r];
                            c2[r] = xc * wB1 + c2[r];
                        }
                    }
#pragma unroll
                    for (int r = 0; r < 16; ++r) {
                        mo0 = fmaxf(mo0, fmaxf(a2[r].x + a2[r].y, 0.0f));
                        mo1 = fmaxf(mo1, fmaxf(c2[r].x + c2[r].y, 0.0f));
                    }
                }
            }
            out[((size_t)b * 128 + lane) * 1024 + s] = mo0;
            out[((size_t)b * 128 + lane + 64) * 1024 + s] = mo1;
        }
    }
}

extern "C" void kernel_launch(void* const* d_in, const int* in_sizes, int n_in,
                              void* d_out, int out_size, void* d_ws,
                              size_t ws_size, hipStream_t stream) {
    const float* xyz = (const float*)d_in[0];
    const float* feat = (const float*)d_in[1];
    const float* w1 = (const float*)d_in[2];
    const float* b1 = (const float*)d_in[3];
    const float* w2 = (const float*)d_in[4];
    const float* b2 = (const float*)d_in[5];
    const float* w3 = (const float*)d_in[6];
    const float* b3 = (const float*)d_in[7];

    float* out_xyz = (float*)d_out;                       // (8,1024,3)
    float* out_feat = (float*)d_out + B_SZ * NPOINT_ * 3; // (8,128,1024)
    int* prog = (int*)d_ws;  // 8 progress counters, 256B apart

    hipMemsetAsync(d_ws, 0, NPROD * 64 * sizeof(int), stream);
    fused_kernel<<<NPROD + NCONS, 512, 0, stream>>>(
        xyz, feat, w1, b1, w2, b2, w3, b3, out_xyz, out_feat, prog);
}